// Round 9
// baseline (191.098 us; speedup 1.0000x reference)
//
#include <hip/hip_runtime.h>
#include <hip/hip_bf16.h>

#define DI __device__ __forceinline__

namespace {
constexpr int N_ = 128, S_ = 32, P_ = 16, F_ = 256, H_ = 4, NH_ = 128;
constexpr int SP_ = S_ * P_;          // 512
constexpr int ROWS_ = N_ * SP_;       // 65536
constexpr int GC_ = H_ * NH_;         // 512
constexpr float SLOPE_ = 0.2f;
constexpr int OUT_ELEMS = N_ * SP_ * NH_;    // 8,388,608
constexpr int HS_ = N_ * F_;          // 32768 f16 per sp per split buffer
}

DI float lrelu(float x) { return x >= 0.f ? x : SLOPE_ * x; }

DI unsigned short f2h(float x) {
    _Float16 h = (_Float16)x;
    return __builtin_bit_cast(unsigned short, h);
}
DI float h2f(unsigned short b) {
    return (float)__builtin_bit_cast(_Float16, b);
}

typedef _Float16 f16x8 __attribute__((ext_vector_type(8)));
typedef float    f32x4 __attribute__((ext_vector_type(4)));

DI f32x4 mfma16h(uint4 a, uint4 b, f32x4 c) {
    return __builtin_amdgcn_mfma_f32_16x16x32_f16(
        __builtin_bit_cast(f16x8, a), __builtin_bit_cast(f16x8, b), c, 0, 0, 0);
}

DI void gload16(const unsigned short* g, unsigned short* lds) {
    __builtin_amdgcn_global_load_lds(
        (const __attribute__((address_space(1))) unsigned int*)g,
        (__attribute__((address_space(3))) unsigned int*)lds, 16, 0, 0);
}

// ---------------------------------------------------------------------------
// prep: wl_s[f][h] = sum_nh W_l[f][h*128+nh]*aw[nh];  wr_s likewise with aw[128+]
__global__ __launch_bounds__(256) void prep_kernel(
    const float* __restrict__ Wl, const float* __restrict__ Wr,
    const float* __restrict__ aw, float* __restrict__ wls, float* __restrict__ wrs) {
    int t = blockIdx.x * 256 + threadIdx.x;   // 0..2047
    int which = t >> 10;                       // 0 -> wl, 1 -> wr
    int f = (t & 1023) >> 2;
    int h = t & 3;
    const float* W = which ? Wr : Wl;
    const float* a = aw + which * NH_;
    const float* wrow = W + (size_t)f * GC_ + h * NH_;
    float s = 0.f;
    for (int k = 0; k < NH_; ++k) s += wrow[k] * a[k];
    (which ? wrs : wls)[f * H_ + h] = s;
}

// ---------------------------------------------------------------------------
// prep_bt: split Wr*256 into f16 hi/lo in TRANSPOSED layout bt[col][k].
__global__ __launch_bounds__(256) void prep_bt(
    const float* __restrict__ Wr, unsigned short* __restrict__ bth,
    unsigned short* __restrict__ btl) {
    int t = blockIdx.x * 256 + threadIdx.x;   // 0..16383
    int col = t >> 5, k0 = (t & 31) * 8;
    union { unsigned short us[8]; uint4 v; } ph, pl;
#pragma unroll
    for (int e = 0; e < 8; ++e) {
        float v = Wr[(size_t)(k0 + e) * GC_ + col] * 256.0f;
        unsigned short hi = f2h(v);
        ph.us[e] = hi;
        pl.us[e] = f2h(v - h2f(hi));
    }
    *(uint4*)&bth[col * F_ + k0] = ph.v;
    *(uint4*)&btl[col * F_ + k0] = pl.v;
}

// ---------------------------------------------------------------------------
// prep_h16: hm (f32, [node*512+sp][k]) -> f16 hi/lo in [sp][node][k] layout.
// One block per sp; fully coalesced writes (1 KB contiguous per wave).
__global__ __launch_bounds__(256) void prep_h16(
    const float* __restrict__ hm, unsigned short* __restrict__ h16h,
    unsigned short* __restrict__ h16l) {
    int sp = blockIdx.x, t = threadIdx.x;
    int kc = t & 31;            // *8 f16 = 16B chunk of k
    int r0 = t >> 5;            // 8 rows per pass
    unsigned short* dh = h16h + (size_t)sp * HS_;
    unsigned short* dl = h16l + (size_t)sp * HS_;
    for (int it = 0; it < 16; ++it) {
        int row = it * 8 + r0;
        const float* ap = hm + ((size_t)row * 512 + sp) * 256 + kc * 8;
        float4 a0 = *(const float4*)ap;
        float4 a1 = *(const float4*)(ap + 4);
        float av[8] = {a0.x, a0.y, a0.z, a0.w, a1.x, a1.y, a1.z, a1.w};
        union { unsigned short us[8]; uint4 v; } ph, pl;
#pragma unroll
        for (int e = 0; e < 8; ++e) {
            unsigned short hi = f2h(av[e]);
            ph.us[e] = hi;
            pl.us[e] = f2h(av[e] - h2f(hi));
        }
        *(uint4*)&dh[row * 256 + kc * 8] = ph.v;
        *(uint4*)&dl[row * 256 + kc * 8] = pl.v;
    }
}

// ---------------------------------------------------------------------------
// scores: one thread per row r = n*512 + sp of h.  sl/sr layout: [sp][n][h]
__global__ __launch_bounds__(256) void score_kernel(
    const float* __restrict__ hm, const float* __restrict__ wls,
    const float* __restrict__ wrs, float* __restrict__ sl, float* __restrict__ sr) {
    int r = blockIdx.x * 256 + threadIdx.x;    // 0..65535
    const float4* hr  = (const float4*)(hm + (size_t)r * F_);
    const float4* wl4 = (const float4*)wls;    // [f] -> 4 heads
    const float4* wr4 = (const float4*)wrs;
    float4 al = {0.f,0.f,0.f,0.f}, ar = {0.f,0.f,0.f,0.f};
    for (int f0 = 0; f0 < F_; f0 += 4) {
        float4 hv = hr[f0 >> 2];
        float hx[4] = {hv.x, hv.y, hv.z, hv.w};
#pragma unroll
        for (int u = 0; u < 4; ++u) {
            float4 wl = wl4[f0 + u], wr = wr4[f0 + u];
            al.x += hx[u] * wl.x; al.y += hx[u] * wl.y;
            al.z += hx[u] * wl.z; al.w += hx[u] * wl.w;
            ar.x += hx[u] * wr.x; ar.y += hx[u] * wr.y;
            ar.z += hx[u] * wr.z; ar.w += hx[u] * wr.w;
        }
    }
    int n = r >> 9, sp = r & 511;
    ((float4*)sl)[sp * N_ + n] = al;
    ((float4*)sr)[sp * N_ + n] = ar;
}

// ---------------------------------------------------------------------------
// Fully fused per-sp kernel: softmax + a_out + GEMM (gload_lds dbuf) +
// per-head gt slice (32 KB) + PV.  512 threads, 8 waves.
// GEMM col map: col(w,n) = n*128 + w*16 + ls  -> every wave holds one
// n-tile per head, so head-h gt writes engage all 8 waves.
__global__ __launch_bounds__(512) void gat_fused(
    const float* __restrict__ sl_g, const float* __restrict__ sr_g,
    const unsigned short* __restrict__ h16h, const unsigned short* __restrict__ h16l,
    const unsigned short* __restrict__ bth, const unsigned short* __restrict__ btl,
    float* __restrict__ a_out, float* __restrict__ out) {
    __shared__ unsigned short Ah[2][4096];       // 8 KB x2 (dbuf, hi)
    __shared__ unsigned short Al[2][4096];       // 8 KB x2 (dbuf, lo)
    __shared__ unsigned short gt[128 * 128];     // 32 KB, per-head g^T [f][node^swz]
    __shared__ float4 sl4[N_], sr4[N_], mrow4[N_], invs4[N_];
    __shared__ float slh[H_][132];               // padded per-head score planes
    __shared__ float mx1[H_], mx2[H_];
    __shared__ int   id1[H_];

    int sp = blockIdx.x;
    int t = threadIdx.x;
    int w = t >> 6, l = t & 63;
    int ls = l & 15, kg = l >> 4;

    // ---- load scores ----
    if (t < 128) {
        float4 v = ((const float4*)sl_g)[sp * N_ + t];
        sl4[t] = v;
        slh[0][t] = v.x; slh[1][t] = v.y; slh[2][t] = v.z; slh[3][t] = v.w;
    } else if (t < 256) {
        sr4[t - 128] = ((const float4*)sr_g)[sp * N_ + (t - 128)];
    }
    __syncthreads();

    // ---- per-head max1/max2 of sl ----
    if (t < H_) {
        float m1 = -1e30f; int i1 = 0;
        for (int j = 0; j < N_; ++j) {
            float v = ((const float*)&sl4[j])[t];
            if (v > m1) { m1 = v; i1 = j; }
        }
        float m2 = -1e30f;
        for (int j = 0; j < N_; ++j)
            if (j != i1) m2 = fmaxf(m2, ((const float*)&sl4[j])[t]);
        mx1[t] = m1; mx2[t] = m2; id1[t] = i1;
    }
    __syncthreads();

    // ---- pass 1: per-(i,h) row max and inv-sum ----
    {
        int i = t & 127, h = t >> 7;
        float sri = ((const float*)&sr4[i])[h];
        float m = lrelu(sri + ((id1[h] == i) ? mx2[h] : mx1[h]));
        float sum = 0.f;
        for (int j = 0; j < N_; ++j) {
            float e = lrelu(sri + ((const float*)&sl4[j])[h]);
            float p = __expf(e - m);
            if (j != i) sum += p;
        }
        ((float*)&mrow4[i])[h] = m;
        ((float*)&invs4[i])[h] = 1.f / sum;
    }
    __syncthreads();

    // ---- a_out phase: coalesced (j = t&127 -> 1 KB contiguous per wave) ----
    {
        float4* a_base = (float4*)(a_out + (size_t)sp * 65536);
        int j = t & 127, ib = t >> 7;
        float4 slv = sl4[j];
        for (int it = 0; it < 32; ++it) {
            int i = it * 4 + ib;
            float4 srv = sr4[i], m4 = mrow4[i], s4 = invs4[i];
            float4 p;
            p.x = __expf(lrelu(srv.x + slv.x) - m4.x) * s4.x;
            p.y = __expf(lrelu(srv.y + slv.y) - m4.y) * s4.y;
            p.z = __expf(lrelu(srv.z + slv.z) - m4.z) * s4.z;
            p.w = __expf(lrelu(srv.w + slv.w) - m4.w) * s4.w;
            if (j == i) { p.x = 0.f; p.y = 0.f; p.z = 0.f; p.w = 0.f; }
            a_base[i * N_ + j] = p;
        }
    }

    // ---- GEMM: stage A hi/lo via global_load_lds, double-buffered ----
    const unsigned short* srcH = h16h + (size_t)sp * HS_;
    const unsigned short* srcL = h16l + (size_t)sp * HS_;
    size_t soff = (size_t)(t >> 2) * 256 + (t & 3) * 8;   // row*256 + kc
    int ldst = (t & ~63) * 8;                              // wave-uniform LDS base (f16)

    gload16(srcH + soff, &Ah[0][ldst]);
    gload16(srcL + soff, &Al[0][ldst]);
    __syncthreads();

    f32x4 acc[8][4];
#pragma unroll
    for (int m = 0; m < 8; ++m)
#pragma unroll
        for (int n = 0; n < 4; ++n) acc[m][n] = (f32x4){0.f, 0.f, 0.f, 0.f};

    for (int step = 0; step < 8; ++step) {
        int cur = step & 1;
        int kglob = step * 32 + kg * 8;
        uint4 fbh[4], fbl[4];
#pragma unroll
        for (int n = 0; n < 4; ++n) {
            int c = n * 128 + w * 16 + ls;
            fbh[n] = *(const uint4*)&bth[(size_t)c * F_ + kglob];
            fbl[n] = *(const uint4*)&btl[(size_t)c * F_ + kglob];
        }
        if (step < 7) {          // prefetch next k-slice into other buffer
            gload16(srcH + soff + (step + 1) * 32, &Ah[cur ^ 1][ldst]);
            gload16(srcL + soff + (step + 1) * 32, &Al[cur ^ 1][ldst]);
        }
#pragma unroll
        for (int m = 0; m < 8; ++m) {
            int row = m * 16 + ls;
            uint4 fah = *(const uint4*)&Ah[cur][row * 32 + kg * 8];
            uint4 fal = *(const uint4*)&Al[cur][row * 32 + kg * 8];
#pragma unroll
            for (int n = 0; n < 4; ++n) {
                acc[m][n] = mfma16h(fah, fbh[n], acc[m][n]);   // hi*hi
                acc[m][n] = mfma16h(fah, fbl[n], acc[m][n]);   // hiA*loB
                acc[m][n] = mfma16h(fal, fbh[n], acc[m][n]);   // loA*hiB
            }
        }
        __syncthreads();         // drains prefetch; all waves aligned
    }

    // ---- per-head: gt slice write (all waves) + PV ----
    f32x4 aco[8];
#pragma unroll
    for (int n = 0; n < 8; ++n) aco[n] = (f32x4){0.f, 0.f, 0.f, 0.f};

    int i_my = w * 16 + ls;
    int fl   = w * 16 + ls;          // f-row this lane writes in gt
    int swz  = (ls & 7) << 3;

    for (int h = 0; h < H_; ++h) {
        if (h) __syncthreads();      // PV(h-1) readers done before overwrite

        // write head-h slice: acc[m][h] -> gt[fl][node^swz], undo x256
#pragma unroll
        for (int m = 0; m < 8; ++m) {
            int nodeb = m * 16 + kg * 4;
            union { unsigned short us[4]; uint2 v; } pk;
#pragma unroll
            for (int q = 0; q < 4; ++q) pk.us[q] = f2h(acc[m][h][q] * 0.00390625f);
            *(uint2*)&gt[fl * 128 + (nodeb ^ swz)] = pk.v;
        }
        __syncthreads();

        // pa: this lane's 32 P-values for head h (rows i_my, j in kg-slices)
        float sri = ((const float*)&sr4[i_my])[h];
        float mh  = ((const float*)&mrow4[i_my])[h];
        float sh  = ((const float*)&invs4[i_my])[h];
        uint4 pa[4];
#pragma unroll
        for (int k0i = 0; k0i < 4; ++k0i) {
            int jb = k0i * 32 + kg * 8;
            union { unsigned short us[8]; uint4 v; } pk;
#pragma unroll
            for (int e = 0; e < 8; ++e) {
                int j = jb + e;
                float p = (j == i_my) ? 0.f
                        : __expf(lrelu(sri + slh[h][j]) - mh) * sh;
                pk.us[e] = f2h(p);
            }
            pa[k0i] = pk.v;
        }
        // PV MFMA: aco[n] += P[i, j-slice] x g[j-slice, f]
#pragma unroll
        for (int k0i = 0; k0i < 4; ++k0i) {
            int koff = k0i * 32 + kg * 8;
#pragma unroll
            for (int n = 0; n < 8; ++n) {
                int f = n * 16 + ls;
                uint4 fb = *(const uint4*)&gt[f * 128 + (koff ^ swz)];
                aco[n] = mfma16h(pa[k0i], fb, aco[n]);
            }
        }
    }

    // ---- out epilogue ----
#pragma unroll
    for (int n = 0; n < 8; ++n) {
        int f = n * 16 + ls;
#pragma unroll
        for (int q = 0; q < 4; ++q)
            out[(size_t)(w * 16 + kg * 4 + q) * 65536 + (size_t)sp * NH_ + f] =
                aco[n][q] * 0.25f;
    }
}

// ---------------------------------------------------------------------------
extern "C" void kernel_launch(void* const* d_in, const int* in_sizes, int n_in,
                              void* d_out, int out_size, void* d_ws, size_t ws_size,
                              hipStream_t stream) {
    const float* hm = (const float*)d_in[0];
    const float* Wl = (const float*)d_in[1];
    const float* Wr = (const float*)d_in[2];
    const float* aw = (const float*)d_in[3];

    float* out   = (float*)d_out;
    float* a_out = out + OUT_ELEMS;

    char* ws = (char*)d_ws;
    unsigned short* h16h = (unsigned short*)ws;               // 32 MiB
    unsigned short* h16l = h16h + (size_t)SP_ * HS_;          // 32 MiB
    float* sl  = (float*)(h16l + (size_t)SP_ * HS_);          // 1 MiB
    float* sr  = sl + SP_ * N_ * H_;                          // 1 MiB
    float* wls = sr + SP_ * N_ * H_;                          // 4 KiB
    float* wrs = wls + F_ * H_;                               // 4 KiB
    unsigned short* bth = (unsigned short*)(wrs + F_ * H_);   // 256 KiB
    unsigned short* btl = bth + GC_ * F_;                     // 256 KiB

    prep_kernel <<<8,           256, 0, stream>>>(Wl, Wr, aw, wls, wrs);
    prep_bt     <<<64,          256, 0, stream>>>(Wr, bth, btl);
    prep_h16    <<<SP_,         256, 0, stream>>>(hm, h16h, h16l);
    score_kernel<<<ROWS_ / 256, 256, 0, stream>>>(hm, wls, wrs, sl, sr);
    gat_fused   <<<SP_,         512, 0, stream>>>(sl, sr, h16h, h16l, bth, btl,
                                                  a_out, out);
}

// Round 10
// 150.313 us; speedup vs baseline: 1.2713x; 1.2713x over previous
//
#include <hip/hip_runtime.h>
#include <hip/hip_bf16.h>

#define DI __device__ __forceinline__

namespace {
constexpr int N_ = 128, S_ = 32, P_ = 16, F_ = 256, H_ = 4, NH_ = 128;
constexpr int SP_ = S_ * P_;          // 512
constexpr int ROWS_ = N_ * SP_;       // 65536
constexpr int GC_ = H_ * NH_;         // 512
constexpr float SLOPE_ = 0.2f;
constexpr int OUT_ELEMS = N_ * SP_ * NH_;    // 8,388,608
}

DI float lrelu(float x) { return x >= 0.f ? x : SLOPE_ * x; }

DI unsigned short f2h(float x) {
    _Float16 h = (_Float16)x;
    return __builtin_bit_cast(unsigned short, h);
}
DI float h2f(unsigned short b) {
    return (float)__builtin_bit_cast(_Float16, b);
}

typedef _Float16 f16x8 __attribute__((ext_vector_type(8)));
typedef float    f32x4 __attribute__((ext_vector_type(4)));

DI f32x4 mfma16h(uint4 a, uint4 b, f32x4 c) {
    return __builtin_amdgcn_mfma_f32_16x16x32_f16(
        __builtin_bit_cast(f16x8, a), __builtin_bit_cast(f16x8, b), c, 0, 0, 0);
}

// ---------------------------------------------------------------------------
// prep: wl_s[f][h] = sum_nh W_l[f][h*128+nh]*aw[nh];  wr_s likewise with aw[128+]
__global__ __launch_bounds__(256) void prep_kernel(
    const float* __restrict__ Wl, const float* __restrict__ Wr,
    const float* __restrict__ aw, float* __restrict__ wls, float* __restrict__ wrs) {
    int t = blockIdx.x * 256 + threadIdx.x;   // 0..2047
    int which = t >> 10;                       // 0 -> wl, 1 -> wr
    int f = (t & 1023) >> 2;
    int h = t & 3;
    const float* W = which ? Wr : Wl;
    const float* a = aw + which * NH_;
    const float* wrow = W + (size_t)f * GC_ + h * NH_;
    float s = 0.f;
    for (int k = 0; k < NH_; ++k) s += wrow[k] * a[k];
    (which ? wrs : wls)[f * H_ + h] = s;
}

// ---------------------------------------------------------------------------
// prep_bt: split Wr*256 into f16 hi/lo in TRANSPOSED layout bt[col][k].
__global__ __launch_bounds__(256) void prep_bt(
    const float* __restrict__ Wr, unsigned short* __restrict__ bth,
    unsigned short* __restrict__ btl) {
    int t = blockIdx.x * 256 + threadIdx.x;   // 0..16383
    int col = t >> 5, k0 = (t & 31) * 8;
    union { unsigned short us[8]; uint4 v; } ph, pl;
#pragma unroll
    for (int e = 0; e < 8; ++e) {
        float v = Wr[(size_t)(k0 + e) * GC_ + col] * 256.0f;
        unsigned short hi = f2h(v);
        ph.us[e] = hi;
        pl.us[e] = f2h(v - h2f(hi));
    }
    *(uint4*)&bth[col * F_ + k0] = ph.v;
    *(uint4*)&btl[col * F_ + k0] = pl.v;
}

// ---------------------------------------------------------------------------
// scores: one thread per row r = n*512 + sp of h.  sl/sr layout: [sp][n][h]
__global__ __launch_bounds__(256) void score_kernel(
    const float* __restrict__ hm, const float* __restrict__ wls,
    const float* __restrict__ wrs, float* __restrict__ sl, float* __restrict__ sr) {
    int r = blockIdx.x * 256 + threadIdx.x;    // 0..65535
    const float4* hr  = (const float4*)(hm + (size_t)r * F_);
    const float4* wl4 = (const float4*)wls;    // [f] -> 4 heads
    const float4* wr4 = (const float4*)wrs;
    float4 al = {0.f,0.f,0.f,0.f}, ar = {0.f,0.f,0.f,0.f};
    for (int f0 = 0; f0 < F_; f0 += 4) {
        float4 hv = hr[f0 >> 2];
        float hx[4] = {hv.x, hv.y, hv.z, hv.w};
#pragma unroll
        for (int u = 0; u < 4; ++u) {
            float4 wl = wl4[f0 + u], wr = wr4[f0 + u];
            al.x += hx[u] * wl.x; al.y += hx[u] * wl.y;
            al.z += hx[u] * wl.z; al.w += hx[u] * wl.w;
            ar.x += hx[u] * wr.x; ar.y += hx[u] * wr.y;
            ar.z += hx[u] * wr.z; ar.w += hx[u] * wr.w;
        }
    }
    int n = r >> 9, sp = r & 511;
    ((float4*)sl)[sp * N_ + n] = al;
    ((float4*)sr)[sp * N_ + n] = ar;
}

// ---------------------------------------------------------------------------
// Fully fused per-sp kernel with a_out interleaved into the GEMM K-loop.
// 512 threads (8 waves), 1 block/CU (reg-bound); overlap is in-block:
// per K-step: {issue next-A f32 loads, issue B frag loads, 4 a_out iters
// (exps + stores drain under MFMA), 96 MFMA, convert+ds_write next A, barrier}.
__global__ __launch_bounds__(512, 2) void gat_fused(
    const float* __restrict__ sl_g, const float* __restrict__ sr_g,
    const float* __restrict__ hm,
    const unsigned short* __restrict__ bth, const unsigned short* __restrict__ btl,
    float* __restrict__ a_out, float* __restrict__ out) {
    constexpr int PA = 40;                        // f16 pitch: 80B rows
    __shared__ unsigned short Ah[2][128 * PA];    // 10 KB x2
    __shared__ unsigned short Al[2][128 * PA];    // 10 KB x2
    __shared__ unsigned short gt[128 * 128];      // 32 KB per-head g^T
    __shared__ float4 sl4[N_], sr4[N_], mrow4[N_], invs4[N_];
    __shared__ float slh[H_][132];
    __shared__ float mx1[H_], mx2[H_];
    __shared__ int   id1[H_];

    int sp = blockIdx.x;
    int t = threadIdx.x;
    int w = t >> 6, l = t & 63;
    int ls = l & 15, kg = l >> 4;

    // ---- load scores ----
    if (t < 128) {
        float4 v = ((const float4*)sl_g)[sp * N_ + t];
        sl4[t] = v;
        slh[0][t] = v.x; slh[1][t] = v.y; slh[2][t] = v.z; slh[3][t] = v.w;
    } else if (t < 256) {
        sr4[t - 128] = ((const float4*)sr_g)[sp * N_ + (t - 128)];
    }
    __syncthreads();

    // ---- per-head max1/max2 of sl ----
    if (t < H_) {
        float m1 = -1e30f; int i1 = 0;
        for (int j = 0; j < N_; ++j) {
            float v = ((const float*)&sl4[j])[t];
            if (v > m1) { m1 = v; i1 = j; }
        }
        float m2 = -1e30f;
        for (int j = 0; j < N_; ++j)
            if (j != i1) m2 = fmaxf(m2, ((const float*)&sl4[j])[t]);
        mx1[t] = m1; mx2[t] = m2; id1[t] = i1;
    }
    __syncthreads();

    // ---- A staging geometry; issue step-0 loads early ----
    int arow = t >> 2, akc = (t & 3) * 8;
    const float* abase = hm + ((size_t)arow * 512 + sp) * 256 + akc;
    float4 s0 = *(const float4*)(abase);
    float4 s1 = *(const float4*)(abase + 4);

    // ---- pass 1: per-(i,h) row max and inv-sum (hides the loads above) ----
    {
        int i = t & 127, h = t >> 7;
        float sri = ((const float*)&sr4[i])[h];
        float m = lrelu(sri + ((id1[h] == i) ? mx2[h] : mx1[h]));
        float sum = 0.f;
        for (int j = 0; j < N_; ++j) {
            float e = lrelu(sri + ((const float*)&sl4[j])[h]);
            float p = __expf(e - m);
            if (j != i) sum += p;
        }
        ((float*)&mrow4[i])[h] = m;
        ((float*)&invs4[i])[h] = 1.f / sum;
    }

    // ---- convert + write A step-0 ----
    {
        float av[8] = {s0.x, s0.y, s0.z, s0.w, s1.x, s1.y, s1.z, s1.w};
        union { unsigned short us[8]; uint4 v; } ph, pl;
#pragma unroll
        for (int e = 0; e < 8; ++e) {
            unsigned short hi = f2h(av[e]);
            ph.us[e] = hi;
            pl.us[e] = f2h(av[e] - h2f(hi));
        }
        *(uint4*)&Ah[0][arow * PA + akc] = ph.v;
        *(uint4*)&Al[0][arow * PA + akc] = pl.v;
    }
    __syncthreads();

    f32x4 acc[8][4];
#pragma unroll
    for (int m = 0; m < 8; ++m)
#pragma unroll
        for (int n = 0; n < 4; ++n) acc[m][n] = (f32x4){0.f, 0.f, 0.f, 0.f};

    float4* a_base_g = (float4*)(a_out + (size_t)sp * 65536);
    int aj = t & 127, ib = t >> 7;           // ib is wave-uniform
    float4 slv = sl4[aj];

    for (int step = 0; step < 8; ++step) {
        int cur = step & 1;
        // (1) issue next-A f32 loads (land during exps+MFMA)
        float4 n0, n1;
        if (step < 7) {
            n0 = *(const float4*)(abase + (step + 1) * 32);
            n1 = *(const float4*)(abase + (step + 1) * 32 + 4);
        }
        // (2) issue B fragment loads (L2)
        int kglob = step * 32 + kg * 8;
        uint4 fbh[4], fbl[4];
#pragma unroll
        for (int n = 0; n < 4; ++n) {
            int c = n * 128 + w * 16 + ls;
            fbh[n] = *(const uint4*)&bth[(size_t)c * F_ + kglob];
            fbl[n] = *(const uint4*)&btl[(size_t)c * F_ + kglob];
        }
        // (3) 4 a_out iterations: stores drain under MFMA below
#pragma unroll
        for (int q = 0; q < 4; ++q) {
            int i = step * 16 + q * 4 + ib;
            float4 srv = sr4[i], m4 = mrow4[i], s4 = invs4[i];
            float4 p;
            p.x = __expf(lrelu(srv.x + slv.x) - m4.x) * s4.x;
            p.y = __expf(lrelu(srv.y + slv.y) - m4.y) * s4.y;
            p.z = __expf(lrelu(srv.z + slv.z) - m4.z) * s4.z;
            p.w = __expf(lrelu(srv.w + slv.w) - m4.w) * s4.w;
            if (aj == i) { p.x = 0.f; p.y = 0.f; p.z = 0.f; p.w = 0.f; }
            a_base_g[i * N_ + aj] = p;
        }
        // (4) MFMA: 8m x 4n x 3 products
#pragma unroll
        for (int m = 0; m < 8; ++m) {
            int row = m * 16 + ls;
            uint4 fah = *(const uint4*)&Ah[cur][row * PA + kg * 8];
            uint4 fal = *(const uint4*)&Al[cur][row * PA + kg * 8];
#pragma unroll
            for (int n = 0; n < 4; ++n) {
                acc[m][n] = mfma16h(fah, fbh[n], acc[m][n]);   // hi*hi
                acc[m][n] = mfma16h(fah, fbl[n], acc[m][n]);   // hiA*loB
                acc[m][n] = mfma16h(fal, fbh[n], acc[m][n]);   // loA*hiB
            }
        }
        // (5) convert + write next A into other buffer
        if (step < 7) {
            float av[8] = {n0.x, n0.y, n0.z, n0.w, n1.x, n1.y, n1.z, n1.w};
            union { unsigned short us[8]; uint4 v; } ph, pl;
#pragma unroll
            for (int e = 0; e < 8; ++e) {
                unsigned short hi = f2h(av[e]);
                ph.us[e] = hi;
                pl.us[e] = f2h(av[e] - h2f(hi));
            }
            *(uint4*)&Ah[cur ^ 1][arow * PA + akc] = ph.v;
            *(uint4*)&Al[cur ^ 1][arow * PA + akc] = pl.v;
        }
        __syncthreads();
    }

    // ---- per-head: gt slice write (all waves) + PV ----
    f32x4 aco[8];
#pragma unroll
    for (int n = 0; n < 8; ++n) aco[n] = (f32x4){0.f, 0.f, 0.f, 0.f};

    int i_my = w * 16 + ls;
    int fl   = w * 16 + ls;
    int swz  = (ls & 7) << 3;

    for (int h = 0; h < H_; ++h) {
        if (h) __syncthreads();

#pragma unroll
        for (int m = 0; m < 8; ++m) {
            int nodeb = m * 16 + kg * 4;
            union { unsigned short us[4]; uint2 v; } pk;
#pragma unroll
            for (int q = 0; q < 4; ++q) pk.us[q] = f2h(acc[m][h][q] * 0.00390625f);
            *(uint2*)&gt[fl * 128 + (nodeb ^ swz)] = pk.v;
        }
        __syncthreads();

        float sri = ((const float*)&sr4[i_my])[h];
        float mh  = ((const float*)&mrow4[i_my])[h];
        float sh  = ((const float*)&invs4[i_my])[h];
        uint4 pa[4];
#pragma unroll
        for (int k0i = 0; k0i < 4; ++k0i) {
            int jb = k0i * 32 + kg * 8;
            union { unsigned short us[8]; uint4 v; } pk;
#pragma unroll
            for (int e = 0; e < 8; ++e) {
                int j = jb + e;
                float p = (j == i_my) ? 0.f
                        : __expf(lrelu(sri + slh[h][j]) - mh) * sh;
                pk.us[e] = f2h(p);
            }
            pa[k0i] = pk.v;
        }
#pragma unroll
        for (int k0i = 0; k0i < 4; ++k0i) {
            int koff = k0i * 32 + kg * 8;
#pragma unroll
            for (int n = 0; n < 8; ++n) {
                int f = n * 16 + ls;
                uint4 fb = *(const uint4*)&gt[f * 128 + (koff ^ swz)];
                aco[n] = mfma16h(pa[k0i], fb, aco[n]);
            }
        }
    }

    // ---- out epilogue ----
#pragma unroll
    for (int n = 0; n < 8; ++n) {
        int f = n * 16 + ls;
#pragma unroll
        for (int q = 0; q < 4; ++q)
            out[(size_t)(w * 16 + kg * 4 + q) * 65536 + (size_t)sp * NH_ + f] =
                aco[n][q] * 0.25f;
    }
}

// ---------------------------------------------------------------------------
extern "C" void kernel_launch(void* const* d_in, const int* in_sizes, int n_in,
                              void* d_out, int out_size, void* d_ws, size_t ws_size,
                              hipStream_t stream) {
    const float* hm = (const float*)d_in[0];
    const float* Wl = (const float*)d_in[1];
    const float* Wr = (const float*)d_in[2];
    const float* aw = (const float*)d_in[3];

    float* out   = (float*)d_out;
    float* a_out = out + OUT_ELEMS;

    char* ws = (char*)d_ws;
    float* sl  = (float*)ws;                                  // 1 MiB
    float* sr  = sl + SP_ * N_ * H_;                          // 1 MiB
    float* wls = sr + SP_ * N_ * H_;                          // 4 KiB
    float* wrs = wls + F_ * H_;                               // 4 KiB
    unsigned short* bth = (unsigned short*)(wrs + F_ * H_);   // 256 KiB
    unsigned short* btl = bth + GC_ * F_;                     // 256 KiB

    prep_kernel <<<8,           256, 0, stream>>>(Wl, Wr, aw, wls, wrs);
    prep_bt     <<<64,          256, 0, stream>>>(Wr, bth, btl);
    score_kernel<<<ROWS_ / 256, 256, 0, stream>>>(hm, wls, wrs, sl, sr);
    gat_fused   <<<SP_,         512, 0, stream>>>(sl, sr, hm, bth, btl, a_out, out);
}

// Round 12
// 140.367 us; speedup vs baseline: 1.3614x; 1.0709x over previous
//
#include <hip/hip_runtime.h>
#include <hip/hip_bf16.h>

#define DI __device__ __forceinline__

namespace {
constexpr int N_ = 128, S_ = 32, P_ = 16, F_ = 256, H_ = 4, NH_ = 128;
constexpr int SP_ = S_ * P_;          // 512
constexpr int ROWS_ = N_ * SP_;       // 65536
constexpr int GC_ = H_ * NH_;         // 512
constexpr float SLOPE_ = 0.2f;
constexpr int OUT_ELEMS = N_ * SP_ * NH_;    // 8,388,608
}

DI float lrelu(float x) { return x >= 0.f ? x : SLOPE_ * x; }

DI unsigned short f2h(float x) {
    _Float16 h = (_Float16)x;
    return __builtin_bit_cast(unsigned short, h);
}
DI float h2f(unsigned short b) {
    return (float)__builtin_bit_cast(_Float16, b);
}

typedef __fp16   fp16x2 __attribute__((ext_vector_type(2)));
typedef _Float16 f16x8 __attribute__((ext_vector_type(8)));
typedef float    f32x4 __attribute__((ext_vector_type(4)));

DI unsigned int pk2(float a, float b) {          // packed f16 convert (RTZ)
    fp16x2 r = __builtin_amdgcn_cvt_pkrtz(a, b);
    return __builtin_bit_cast(unsigned int, r);
}

DI f32x4 mfma16h(uint4 a, uint4 b, f32x4 c) {
    return __builtin_amdgcn_mfma_f32_16x16x32_f16(
        __builtin_bit_cast(f16x8, a), __builtin_bit_cast(f16x8, b), c, 0, 0, 0);
}

// ---------------------------------------------------------------------------
__global__ __launch_bounds__(256) void prep_kernel(
    const float* __restrict__ Wl, const float* __restrict__ Wr,
    const float* __restrict__ aw, float* __restrict__ wls, float* __restrict__ wrs) {
    int t = blockIdx.x * 256 + threadIdx.x;   // 0..2047
    int which = t >> 10;
    int f = (t & 1023) >> 2;
    int h = t & 3;
    const float* W = which ? Wr : Wl;
    const float* a = aw + which * NH_;
    const float* wrow = W + (size_t)f * GC_ + h * NH_;
    float s = 0.f;
    for (int k = 0; k < NH_; ++k) s += wrow[k] * a[k];
    (which ? wrs : wls)[f * H_ + h] = s;
}

// ---------------------------------------------------------------------------
__global__ __launch_bounds__(256) void prep_bt(
    const float* __restrict__ Wr, unsigned short* __restrict__ bth,
    unsigned short* __restrict__ btl) {
    int t = blockIdx.x * 256 + threadIdx.x;   // 0..16383
    int col = t >> 5, k0 = (t & 31) * 8;
    union { unsigned short us[8]; uint4 v; } ph, pl;
#pragma unroll
    for (int e = 0; e < 8; ++e) {
        float v = Wr[(size_t)(k0 + e) * GC_ + col] * 256.0f;
        unsigned short hi = f2h(v);
        ph.us[e] = hi;
        pl.us[e] = f2h(v - h2f(hi));
    }
    *(uint4*)&bth[col * F_ + k0] = ph.v;
    *(uint4*)&btl[col * F_ + k0] = pl.v;
}

// ---------------------------------------------------------------------------
__global__ __launch_bounds__(256) void score_kernel(
    const float* __restrict__ hm, const float* __restrict__ wls,
    const float* __restrict__ wrs, float* __restrict__ sl, float* __restrict__ sr) {
    int r = blockIdx.x * 256 + threadIdx.x;    // 0..65535
    const float4* hr  = (const float4*)(hm + (size_t)r * F_);
    const float4* wl4 = (const float4*)wls;
    const float4* wr4 = (const float4*)wrs;
    float4 al = {0.f,0.f,0.f,0.f}, ar = {0.f,0.f,0.f,0.f};
    for (int f0 = 0; f0 < F_; f0 += 4) {
        float4 hv = hr[f0 >> 2];
        float hx[4] = {hv.x, hv.y, hv.z, hv.w};
#pragma unroll
        for (int u = 0; u < 4; ++u) {
            float4 wl = wl4[f0 + u], wr = wr4[f0 + u];
            al.x += hx[u] * wl.x; al.y += hx[u] * wl.y;
            al.z += hx[u] * wl.z; al.w += hx[u] * wl.w;
            ar.x += hx[u] * wr.x; ar.y += hx[u] * wr.y;
            ar.z += hx[u] * wr.z; ar.w += hx[u] * wr.w;
        }
    }
    int n = r >> 9, sp = r & 511;
    ((float4*)sl)[sp * N_ + n] = al;
    ((float4*)sr)[sp * N_ + n] = ar;
}

// ---------------------------------------------------------------------------
// Fused per-sp kernel.  LDS union: A dbuf (40 KB) lives in the same space as
// the all-heads gt (128 KB, written after the K-loop).  Schedule:
//   scores -> parallel max1/max2 -> K-loop {B frags, pass1(j-chunk) steps 0-3 /
//   a_out(i-chunk) steps 4-7, 96 MFMA, next-A convert} -> gt epilogue (1 bar)
//   -> barrier-free PV with setprio around MFMA clusters -> out.
__global__ __launch_bounds__(512, 2) void gat_fused(
    const float* __restrict__ sl_g, const float* __restrict__ sr_g,
    const float* __restrict__ hm,
    const unsigned short* __restrict__ bth, const unsigned short* __restrict__ btl,
    float* __restrict__ a_out, float* __restrict__ out) {
    constexpr int PA = 40;
    __shared__ __align__(16) unsigned char SMEM[141440];
    unsigned short* Ah0 = (unsigned short*)SMEM;               // [128*PA]
    unsigned short* Ah1 = Ah0 + 128 * PA;
    unsigned short* Al0 = Ah1 + 128 * PA;
    unsigned short* Al1 = Al0 + 128 * PA;                      // 40960 B total
    unsigned short* gt4 = (unsigned short*)SMEM;               // [4][128][128] after GEMM
    float4* sl4   = (float4*)(SMEM + 131072);
    float4* sr4   = (float4*)(SMEM + 133120);
    float4* mrow4 = (float4*)(SMEM + 135168);
    float4* invs4 = (float4*)(SMEM + 137216);
    float*  slh   = (float*)(SMEM + 139264);                   // [4][132]
    float*  mx1   = (float*)(SMEM + 141376);
    float*  mx2   = (float*)(SMEM + 141392);
    int*    id1   = (int*)(SMEM + 141408);
    // scratch (inside mrow4 region, dead until step 3):
    float* pm1 = (float*)mrow4;          // [4][32]
    float* pm2 = pm1 + 128;              // [4][32]
    int*   pid = (int*)(pm2 + 128);      // [4][32]

    int sp = blockIdx.x;
    int t = threadIdx.x;
    int w = t >> 6, l = t & 63;
    int ls = l & 15, kg = l >> 4;

    // ---- load scores ----
    if (t < 128) {
        float4 v = ((const float4*)sl_g)[sp * N_ + t];
        sl4[t] = v;
        slh[0 * 132 + t] = v.x; slh[1 * 132 + t] = v.y;
        slh[2 * 132 + t] = v.z; slh[3 * 132 + t] = v.w;
    } else if (t < 256) {
        sr4[t - 128] = ((const float4*)sr_g)[sp * N_ + (t - 128)];
    }
    __syncthreads();

    // ---- issue step-0 A loads early (drain under max-scan) ----
    int arow = t >> 2, akc = (t & 3) * 8;
    const float* abase = hm + ((size_t)arow * 512 + sp) * 256 + akc;
    float4 s0 = *(const float4*)(abase);
    float4 s1 = *(const float4*)(abase + 4);

    // ---- parallel max1/max2(+argmax) of sl per head ----
    if (t < 128) {
        int h = t >> 5, seg = t & 31;
        float m1 = -1e30f, m2 = -1e30f; int i1 = -1;
#pragma unroll
        for (int jj = 0; jj < 4; ++jj) {
            int j = seg * 4 + jj;
            float v = slh[h * 132 + j];
            if (v > m1) { m2 = m1; m1 = v; i1 = j; }
            else m2 = fmaxf(m2, v);
        }
        pm1[h * 32 + seg] = m1; pm2[h * 32 + seg] = m2; pid[h * 32 + seg] = i1;
    }
    __syncthreads();
    if (t < H_) {
        float m1 = -1e30f, m2 = -1e30f; int i1 = -1;
        for (int s = 0; s < 32; ++s) {
            float a1 = pm1[t * 32 + s], a2 = pm2[t * 32 + s]; int ai = pid[t * 32 + s];
            if (a1 > m1) { m2 = fmaxf(m1, a2); m1 = a1; i1 = ai; }
            else m2 = fmaxf(m2, a1);
        }
        mx1[t] = m1; mx2[t] = m2; id1[t] = i1;
    }
    __syncthreads();

    // ---- convert + write A step-0 (pkrtz pairs) ----
    {
        float av[8] = {s0.x, s0.y, s0.z, s0.w, s1.x, s1.y, s1.z, s1.w};
        uint4 vh, vl;
        unsigned int* ph = (unsigned int*)&vh;
        unsigned int* pl = (unsigned int*)&vl;
#pragma unroll
        for (int e = 0; e < 8; e += 2) {
            unsigned int hp = pk2(av[e], av[e + 1]);
            float r0 = av[e]     - h2f((unsigned short)(hp & 0xffff));
            float r1 = av[e + 1] - h2f((unsigned short)(hp >> 16));
            ph[e >> 1] = hp;
            pl[e >> 1] = pk2(r0, r1);
        }
        *(uint4*)&Ah0[arow * PA + akc] = vh;
        *(uint4*)&Al0[arow * PA + akc] = vl;
    }

    // ---- pass1 setup (thread owns (i,h); sums accumulated across steps 0-3)
    int p1i = t & 127, p1h = t >> 7;
    float p1sri = ((const float*)&sr4[p1i])[p1h];
    float p1m = lrelu(p1sri + ((id1[p1h] == p1i) ? mx2[p1h] : mx1[p1h]));
    float p1sum = 0.f;

    __syncthreads();

    f32x4 acc[8][4];
#pragma unroll
    for (int m = 0; m < 8; ++m)
#pragma unroll
        for (int n = 0; n < 4; ++n) acc[m][n] = (f32x4){0.f, 0.f, 0.f, 0.f};

    float4* a_base_g = (float4*)(a_out + (size_t)sp * 65536);
    int aj = t & 127, ib = t >> 7;           // a_out: column-owner mapping
    float4 slv = sl4[aj];

    for (int step = 0; step < 8; ++step) {
        unsigned short* AhC = (step & 1) ? Ah1 : Ah0;
        unsigned short* AlC = (step & 1) ? Al1 : Al0;
        unsigned short* AhN = (step & 1) ? Ah0 : Ah1;
        unsigned short* AlN = (step & 1) ? Al0 : Al1;
        // (1) issue next-A f32 loads
        float4 n0, n1;
        if (step < 7) {
            n0 = *(const float4*)(abase + (step + 1) * 32);
            n1 = *(const float4*)(abase + (step + 1) * 32 + 4);
        }
        // (2) issue B fragment loads (L2)
        int kglob = step * 32 + kg * 8;
        uint4 fbh[4], fbl[4];
#pragma unroll
        for (int n = 0; n < 4; ++n) {
            int c = n * 128 + w * 16 + ls;
            fbh[n] = *(const uint4*)&bth[(size_t)c * F_ + kglob];
            fbl[n] = *(const uint4*)&btl[(size_t)c * F_ + kglob];
        }
        // (3) softmax work: pass1 chunks (steps 0-3) / a_out chunks (steps 4-7)
        if (step < 4) {
            int j0 = step * 32;
#pragma unroll 4
            for (int j = j0; j < j0 + 32; ++j) {
                float e = lrelu(p1sri + slh[p1h * 132 + j]);
                float p = __expf(e - p1m);
                if (j != p1i) p1sum += p;
            }
            if (step == 3) {
                ((float*)&mrow4[p1i])[p1h] = p1m;
                ((float*)&invs4[p1i])[p1h] = 1.f / p1sum;
            }
        } else {
            int ibase2 = (step - 4) * 32;
#pragma unroll
            for (int q = 0; q < 8; ++q) {
                int i = ibase2 + q * 4 + ib;
                float4 srv = sr4[i], m4 = mrow4[i], s4 = invs4[i];
                float4 p;
                p.x = __expf(lrelu(srv.x + slv.x) - m4.x) * s4.x;
                p.y = __expf(lrelu(srv.y + slv.y) - m4.y) * s4.y;
                p.z = __expf(lrelu(srv.z + slv.z) - m4.z) * s4.z;
                p.w = __expf(lrelu(srv.w + slv.w) - m4.w) * s4.w;
                if (aj == i) { p.x = 0.f; p.y = 0.f; p.z = 0.f; p.w = 0.f; }
                a_base_g[i * N_ + aj] = p;
            }
        }
        // (4) MFMA
#pragma unroll
        for (int m = 0; m < 8; ++m) {
            int row = m * 16 + ls;
            uint4 fah = *(const uint4*)&AhC[row * PA + kg * 8];
            uint4 fal = *(const uint4*)&AlC[row * PA + kg * 8];
#pragma unroll
            for (int n = 0; n < 4; ++n) {
                acc[m][n] = mfma16h(fah, fbh[n], acc[m][n]);
                acc[m][n] = mfma16h(fah, fbl[n], acc[m][n]);
                acc[m][n] = mfma16h(fal, fbh[n], acc[m][n]);
            }
        }
        // (5) convert + write next A
        if (step < 7) {
            float av[8] = {n0.x, n0.y, n0.z, n0.w, n1.x, n1.y, n1.z, n1.w};
            uint4 vh, vl;
            unsigned int* ph = (unsigned int*)&vh;
            unsigned int* pl = (unsigned int*)&vl;
#pragma unroll
            for (int e = 0; e < 8; e += 2) {
                unsigned int hp = pk2(av[e], av[e + 1]);
                float r0 = av[e]     - h2f((unsigned short)(hp & 0xffff));
                float r1 = av[e + 1] - h2f((unsigned short)(hp >> 16));
                ph[e >> 1] = hp;
                pl[e >> 1] = pk2(r0, r1);
            }
            *(uint4*)&AhN[arow * PA + akc] = vh;
            *(uint4*)&AlN[arow * PA + akc] = vl;
        }
        __syncthreads();
    }

    // ---- GEMM epilogue: all-heads gt (A buffers dead; union reuse) ----
    int fl  = w * 16 + ls;
    int swz = (ls & 7) << 3;
    constexpr float gs = 0.00390625f;
#pragma unroll
    for (int m = 0; m < 8; ++m) {
        int nx = (m * 16 + kg * 4) ^ swz;
#pragma unroll
        for (int h = 0; h < H_; ++h) {
            uint2 pk;
            pk.x = pk2(acc[m][h][0] * gs, acc[m][h][1] * gs);
            pk.y = pk2(acc[m][h][2] * gs, acc[m][h][3] * gs);
            *(uint2*)&gt4[h * 16384 + fl * 128 + nx] = pk;
        }
    }
    __syncthreads();

    // ---- PV: barrier-free; pa-gen(h) overlaps MFMA via scheduling ----
    f32x4 aco[8];
#pragma unroll
    for (int n = 0; n < 8; ++n) aco[n] = (f32x4){0.f, 0.f, 0.f, 0.f};

    int i_my = w * 16 + ls;
    for (int h = 0; h < H_; ++h) {
        float sri = ((const float*)&sr4[i_my])[h];
        float mh  = ((const float*)&mrow4[i_my])[h];
        float sh  = ((const float*)&invs4[i_my])[h];
        uint4 pa[4];
#pragma unroll
        for (int k0i = 0; k0i < 4; ++k0i) {
            int jb = k0i * 32 + kg * 8;
            union { unsigned short us[8]; uint4 v; } pk;
#pragma unroll
            for (int e = 0; e < 8; ++e) {
                int j = jb + e;
                float p = (j == i_my) ? 0.f
                        : __expf(lrelu(sri + slh[h * 132 + j]) - mh) * sh;
                pk.us[e] = f2h(p);
            }
            pa[k0i] = pk.v;
        }
        __builtin_amdgcn_s_setprio(1);
#pragma unroll
        for (int k0i = 0; k0i < 4; ++k0i) {
            int koff = k0i * 32 + kg * 8;
#pragma unroll
            for (int n = 0; n < 8; ++n) {
                int f = n * 16 + ls;
                uint4 fb = *(const uint4*)&gt4[h * 16384 + f * 128 + (koff ^ swz)];
                aco[n] = mfma16h(pa[k0i], fb, aco[n]);
            }
        }
        __builtin_amdgcn_s_setprio(0);
    }

    // ---- out epilogue ----
#pragma unroll
    for (int n = 0; n < 8; ++n) {
        int f = n * 16 + ls;
#pragma unroll
        for (int q = 0; q < 4; ++q)
            out[(size_t)(w * 16 + kg * 4 + q) * 65536 + (size_t)sp * NH_ + f] =
                aco[n][q] * 0.25f;
    }
}

// ---------------------------------------------------------------------------
extern "C" void kernel_launch(void* const* d_in, const int* in_sizes, int n_in,
                              void* d_out, int out_size, void* d_ws, size_t ws_size,
                              hipStream_t stream) {
    const float* hm = (const float*)d_in[0];
    const float* Wl = (const float*)d_in[1];
    const float* Wr = (const float*)d_in[2];
    const float* aw = (const float*)d_in[3];

    float* out   = (float*)d_out;
    float* a_out = out + OUT_ELEMS;

    char* ws = (char*)d_ws;
    float* sl  = (float*)ws;                                  // 1 MiB
    float* sr  = sl + SP_ * N_ * H_;                          // 1 MiB
    float* wls = sr + SP_ * N_ * H_;                          // 4 KiB
    float* wrs = wls + F_ * H_;                               // 4 KiB
    unsigned short* bth = (unsigned short*)(wrs + F_ * H_);   // 256 KiB
    unsigned short* btl = bth + GC_ * F_;                     // 256 KiB

    prep_kernel <<<8,           256, 0, stream>>>(Wl, Wr, aw, wls, wrs);
    prep_bt     <<<64,          256, 0, stream>>>(Wr, bth, btl);
    score_kernel<<<ROWS_ / 256, 256, 0, stream>>>(hm, wls, wrs, sl, sr);
    gat_fused   <<<SP_,         512, 0, stream>>>(sl, sr, hm, bth, btl, a_out, out);
}

// Round 13
// 133.546 us; speedup vs baseline: 1.4309x; 1.0511x over previous
//
#include <hip/hip_runtime.h>
#include <hip/hip_bf16.h>

#define DI __device__ __forceinline__

namespace {
constexpr int N_ = 128, S_ = 32, P_ = 16, F_ = 256, H_ = 4, NH_ = 128;
constexpr int SP_ = S_ * P_;          // 512
constexpr int ROWS_ = N_ * SP_;       // 65536
constexpr int GC_ = H_ * NH_;         // 512
constexpr float SLOPE_ = 0.2f;
constexpr int OUT_ELEMS = N_ * SP_ * NH_;    // 8,388,608
}

DI float lrelu(float x) { return x >= 0.f ? x : SLOPE_ * x; }

DI unsigned short f2h(float x) {
    _Float16 h = (_Float16)x;
    return __builtin_bit_cast(unsigned short, h);
}
DI float h2f(unsigned short b) {
    return (float)__builtin_bit_cast(_Float16, b);
}

typedef __fp16   fp16x2 __attribute__((ext_vector_type(2)));
typedef _Float16 f16x8 __attribute__((ext_vector_type(8)));
typedef float    f32x4 __attribute__((ext_vector_type(4)));

DI unsigned int pk2(float a, float b) {          // packed f16 convert (RTZ)
    fp16x2 r = __builtin_amdgcn_cvt_pkrtz(a, b);
    return __builtin_bit_cast(unsigned int, r);
}

DI f32x4 mfma16h(uint4 a, uint4 b, f32x4 c) {
    return __builtin_amdgcn_mfma_f32_16x16x32_f16(
        __builtin_bit_cast(f16x8, a), __builtin_bit_cast(f16x8, b), c, 0, 0, 0);
}

// ---------------------------------------------------------------------------
__global__ __launch_bounds__(256) void prep_kernel(
    const float* __restrict__ Wl, const float* __restrict__ Wr,
    const float* __restrict__ aw, float* __restrict__ wls, float* __restrict__ wrs) {
    int t = blockIdx.x * 256 + threadIdx.x;   // 0..2047
    int which = t >> 10;
    int f = (t & 1023) >> 2;
    int h = t & 3;
    const float* W = which ? Wr : Wl;
    const float* a = aw + which * NH_;
    const float* wrow = W + (size_t)f * GC_ + h * NH_;
    float s = 0.f;
    for (int k = 0; k < NH_; ++k) s += wrow[k] * a[k];
    (which ? wrs : wls)[f * H_ + h] = s;
}

// ---------------------------------------------------------------------------
__global__ __launch_bounds__(256) void prep_bt(
    const float* __restrict__ Wr, unsigned short* __restrict__ bth,
    unsigned short* __restrict__ btl) {
    int t = blockIdx.x * 256 + threadIdx.x;   // 0..16383
    int col = t >> 5, k0 = (t & 31) * 8;
    union { unsigned short us[8]; uint4 v; } ph, pl;
#pragma unroll
    for (int e = 0; e < 8; ++e) {
        float v = Wr[(size_t)(k0 + e) * GC_ + col] * 256.0f;
        unsigned short hi = f2h(v);
        ph.us[e] = hi;
        pl.us[e] = f2h(v - h2f(hi));
    }
    *(uint4*)&bth[col * F_ + k0] = ph.v;
    *(uint4*)&btl[col * F_ + k0] = pl.v;
}

// ---------------------------------------------------------------------------
__global__ __launch_bounds__(256) void score_kernel(
    const float* __restrict__ hm, const float* __restrict__ wls,
    const float* __restrict__ wrs, float* __restrict__ sl, float* __restrict__ sr) {
    int r = blockIdx.x * 256 + threadIdx.x;    // 0..65535
    const float4* hr  = (const float4*)(hm + (size_t)r * F_);
    const float4* wl4 = (const float4*)wls;
    const float4* wr4 = (const float4*)wrs;
    float4 al = {0.f,0.f,0.f,0.f}, ar = {0.f,0.f,0.f,0.f};
    for (int f0 = 0; f0 < F_; f0 += 4) {
        float4 hv = hr[f0 >> 2];
        float hx[4] = {hv.x, hv.y, hv.z, hv.w};
#pragma unroll
        for (int u = 0; u < 4; ++u) {
            float4 wl = wl4[f0 + u], wr = wr4[f0 + u];
            al.x += hx[u] * wl.x; al.y += hx[u] * wl.y;
            al.z += hx[u] * wl.z; al.w += hx[u] * wl.w;
            ar.x += hx[u] * wr.x; ar.y += hx[u] * wr.y;
            ar.z += hx[u] * wr.z; ar.w += hx[u] * wr.w;
        }
    }
    int n = r >> 9, sp = r & 511;
    ((float4*)sl)[sp * N_ + n] = al;
    ((float4*)sr)[sp * N_ + n] = ar;
}

// ---------------------------------------------------------------------------
// Fused per-sp kernel.  K-loop barriers no longer drain global stores:
// a_out moved to the barrier-free PV phase.  Schedule:
//   scores -> parallel max1/max2 -> K-loop {next-A loads, B frags,
//   pass1 16j/step, 96 MFMA, next-A convert, barrier} -> gt epilogue (1 bar)
//   -> PV phase per head {pa-gen, setprio MFMA, a_out 32-row chunk} -> out.
__global__ __launch_bounds__(512, 2) void gat_fused(
    const float* __restrict__ sl_g, const float* __restrict__ sr_g,
    const float* __restrict__ hm,
    const unsigned short* __restrict__ bth, const unsigned short* __restrict__ btl,
    float* __restrict__ a_out, float* __restrict__ out) {
    constexpr int PA = 40;
    __shared__ __align__(16) unsigned char SMEM[141440];
    unsigned short* Ah0 = (unsigned short*)SMEM;               // [128*PA]
    unsigned short* Ah1 = Ah0 + 128 * PA;
    unsigned short* Al0 = Ah1 + 128 * PA;
    unsigned short* Al1 = Al0 + 128 * PA;                      // 40960 B total
    unsigned short* gt4 = (unsigned short*)SMEM;               // [4][128][128] after GEMM
    float4* sl4   = (float4*)(SMEM + 131072);
    float4* sr4   = (float4*)(SMEM + 133120);
    float4* mrow4 = (float4*)(SMEM + 135168);
    float4* invs4 = (float4*)(SMEM + 137216);
    float*  slh   = (float*)(SMEM + 139264);                   // [4][132]
    float*  mx1   = (float*)(SMEM + 141376);
    float*  mx2   = (float*)(SMEM + 141392);
    int*    id1   = (int*)(SMEM + 141408);
    // scratch (inside mrow4 region, dead until K-loop step 7):
    float* pm1 = (float*)mrow4;          // [4][32]
    float* pm2 = pm1 + 128;              // [4][32]
    int*   pid = (int*)(pm2 + 128);      // [4][32]

    int sp = blockIdx.x;
    int t = threadIdx.x;
    int w = t >> 6, l = t & 63;
    int ls = l & 15, kg = l >> 4;

    // ---- load scores ----
    if (t < 128) {
        float4 v = ((const float4*)sl_g)[sp * N_ + t];
        sl4[t] = v;
        slh[0 * 132 + t] = v.x; slh[1 * 132 + t] = v.y;
        slh[2 * 132 + t] = v.z; slh[3 * 132 + t] = v.w;
    } else if (t < 256) {
        sr4[t - 128] = ((const float4*)sr_g)[sp * N_ + (t - 128)];
    }
    __syncthreads();

    // ---- issue step-0 A loads early (drain under max-scan) ----
    int arow = t >> 2, akc = (t & 3) * 8;
    const float* abase = hm + ((size_t)arow * 512 + sp) * 256 + akc;
    float4 s0 = *(const float4*)(abase);
    float4 s1 = *(const float4*)(abase + 4);

    // ---- parallel max1/max2(+argmax) of sl per head ----
    if (t < 128) {
        int h = t >> 5, seg = t & 31;
        float m1 = -1e30f, m2 = -1e30f; int i1 = -1;
#pragma unroll
        for (int jj = 0; jj < 4; ++jj) {
            int j = seg * 4 + jj;
            float v = slh[h * 132 + j];
            if (v > m1) { m2 = m1; m1 = v; i1 = j; }
            else m2 = fmaxf(m2, v);
        }
        pm1[h * 32 + seg] = m1; pm2[h * 32 + seg] = m2; pid[h * 32 + seg] = i1;
    }
    __syncthreads();
    if (t < H_) {
        float m1 = -1e30f, m2 = -1e30f; int i1 = -1;
        for (int s = 0; s < 32; ++s) {
            float a1 = pm1[t * 32 + s], a2 = pm2[t * 32 + s]; int ai = pid[t * 32 + s];
            if (a1 > m1) { m2 = fmaxf(m1, a2); m1 = a1; i1 = ai; }
            else m2 = fmaxf(m2, a1);
        }
        mx1[t] = m1; mx2[t] = m2; id1[t] = i1;
    }
    __syncthreads();

    // ---- convert + write A step-0 (pkrtz pairs) ----
    {
        float av[8] = {s0.x, s0.y, s0.z, s0.w, s1.x, s1.y, s1.z, s1.w};
        uint4 vh, vl;
        unsigned int* ph = (unsigned int*)&vh;
        unsigned int* pl = (unsigned int*)&vl;
#pragma unroll
        for (int e = 0; e < 8; e += 2) {
            unsigned int hp = pk2(av[e], av[e + 1]);
            float r0 = av[e]     - h2f((unsigned short)(hp & 0xffff));
            float r1 = av[e + 1] - h2f((unsigned short)(hp >> 16));
            ph[e >> 1] = hp;
            pl[e >> 1] = pk2(r0, r1);
        }
        *(uint4*)&Ah0[arow * PA + akc] = vh;
        *(uint4*)&Al0[arow * PA + akc] = vl;
    }

    // ---- pass1 setup (thread owns (i,h); 16 j per K-step) ----
    int p1i = t & 127, p1h = t >> 7;
    float p1sri = ((const float*)&sr4[p1i])[p1h];
    float p1m = lrelu(p1sri + ((id1[p1h] == p1i) ? mx2[p1h] : mx1[p1h]));
    float p1sum = 0.f;

    __syncthreads();

    f32x4 acc[8][4];
#pragma unroll
    for (int m = 0; m < 8; ++m)
#pragma unroll
        for (int n = 0; n < 4; ++n) acc[m][n] = (f32x4){0.f, 0.f, 0.f, 0.f};

    for (int step = 0; step < 8; ++step) {
        unsigned short* AhC = (step & 1) ? Ah1 : Ah0;
        unsigned short* AlC = (step & 1) ? Al1 : Al0;
        unsigned short* AhN = (step & 1) ? Ah0 : Ah1;
        unsigned short* AlN = (step & 1) ? Al0 : Al1;
        // (1) issue next-A f32 loads
        float4 n0, n1;
        if (step < 7) {
            n0 = *(const float4*)(abase + (step + 1) * 32);
            n1 = *(const float4*)(abase + (step + 1) * 32 + 4);
        }
        // (2) issue B fragment loads (L2)
        int kglob = step * 32 + kg * 8;
        uint4 fbh[4], fbl[4];
#pragma unroll
        for (int n = 0; n < 4; ++n) {
            int c = n * 128 + w * 16 + ls;
            fbh[n] = *(const uint4*)&bth[(size_t)c * F_ + kglob];
            fbl[n] = *(const uint4*)&btl[(size_t)c * F_ + kglob];
        }
        // (3) pass1 chunk: 16 j (pure VALU, no global stores)
        {
            int j0 = step * 16;
#pragma unroll 4
            for (int j = j0; j < j0 + 16; ++j) {
                float e = lrelu(p1sri + slh[p1h * 132 + j]);
                float p = __expf(e - p1m);
                if (j != p1i) p1sum += p;
            }
            if (step == 7) {
                ((float*)&mrow4[p1i])[p1h] = p1m;
                ((float*)&invs4[p1i])[p1h] = 1.f / p1sum;
            }
        }
        // (4) MFMA
#pragma unroll
        for (int m = 0; m < 8; ++m) {
            int row = m * 16 + ls;
            uint4 fah = *(const uint4*)&AhC[row * PA + kg * 8];
            uint4 fal = *(const uint4*)&AlC[row * PA + kg * 8];
#pragma unroll
            for (int n = 0; n < 4; ++n) {
                acc[m][n] = mfma16h(fah, fbh[n], acc[m][n]);
                acc[m][n] = mfma16h(fah, fbl[n], acc[m][n]);
                acc[m][n] = mfma16h(fal, fbh[n], acc[m][n]);
            }
        }
        // (5) convert + write next A
        if (step < 7) {
            float av[8] = {n0.x, n0.y, n0.z, n0.w, n1.x, n1.y, n1.z, n1.w};
            uint4 vh, vl;
            unsigned int* ph = (unsigned int*)&vh;
            unsigned int* pl = (unsigned int*)&vl;
#pragma unroll
            for (int e = 0; e < 8; e += 2) {
                unsigned int hp = pk2(av[e], av[e + 1]);
                float r0 = av[e]     - h2f((unsigned short)(hp & 0xffff));
                float r1 = av[e + 1] - h2f((unsigned short)(hp >> 16));
                ph[e >> 1] = hp;
                pl[e >> 1] = pk2(r0, r1);
            }
            *(uint4*)&AhN[arow * PA + akc] = vh;
            *(uint4*)&AlN[arow * PA + akc] = vl;
        }
        __syncthreads();
    }

    // ---- GEMM epilogue: all-heads gt (A buffers dead; union reuse) ----
    int fl  = w * 16 + ls;
    int swz = (ls & 7) << 3;
    constexpr float gs = 0.00390625f;
#pragma unroll
    for (int m = 0; m < 8; ++m) {
        int nx = (m * 16 + kg * 4) ^ swz;
#pragma unroll
        for (int h = 0; h < H_; ++h) {
            uint2 pk;
            pk.x = pk2(acc[m][h][0] * gs, acc[m][h][1] * gs);
            pk.y = pk2(acc[m][h][2] * gs, acc[m][h][3] * gs);
            *(uint2*)&gt4[h * 16384 + fl * 128 + nx] = pk;
        }
    }
    __syncthreads();

    // ---- PV phase (barrier-free): per head {pa-gen, MFMA, a_out chunk} ----
    f32x4 aco[8];
#pragma unroll
    for (int n = 0; n < 8; ++n) aco[n] = (f32x4){0.f, 0.f, 0.f, 0.f};

    int i_my = w * 16 + ls;
    float4* a_base_g = (float4*)(a_out + (size_t)sp * 65536);
    int aj = t & 127, ib = t >> 7;
    float4 slv = sl4[aj];

    for (int h = 0; h < H_; ++h) {
        // pa-gen for head h
        float sri = ((const float*)&sr4[i_my])[h];
        float mh  = ((const float*)&mrow4[i_my])[h];
        float sh  = ((const float*)&invs4[i_my])[h];
        uint4 pa[4];
#pragma unroll
        for (int k0i = 0; k0i < 4; ++k0i) {
            int jb = k0i * 32 + kg * 8;
            union { unsigned short us[8]; uint4 v; } pk;
#pragma unroll
            for (int e = 0; e < 8; ++e) {
                int j = jb + e;
                float p = (j == i_my) ? 0.f
                        : __expf(lrelu(sri + slh[h * 132 + j]) - mh) * sh;
                pk.us[e] = f2h(p);
            }
            pa[k0i] = pk.v;
        }
        __builtin_amdgcn_s_setprio(1);
#pragma unroll
        for (int k0i = 0; k0i < 4; ++k0i) {
            int koff = k0i * 32 + kg * 8;
#pragma unroll
            for (int n = 0; n < 8; ++n) {
                int f = n * 16 + ls;
                uint4 fb = *(const uint4*)&gt4[h * 16384 + f * 128 + (koff ^ swz)];
                aco[n] = mfma16h(pa[k0i], fb, aco[n]);
            }
        }
        __builtin_amdgcn_s_setprio(0);
        // a_out chunk: rows h*32 .. h*32+31 (stores drain under next head)
#pragma unroll
        for (int q = 0; q < 8; ++q) {
            int i = h * 32 + q * 4 + ib;
            float4 srv = sr4[i], m4 = mrow4[i], s4 = invs4[i];
            float4 p;
            p.x = __expf(lrelu(srv.x + slv.x) - m4.x) * s4.x;
            p.y = __expf(lrelu(srv.y + slv.y) - m4.y) * s4.y;
            p.z = __expf(lrelu(srv.z + slv.z) - m4.z) * s4.z;
            p.w = __expf(lrelu(srv.w + slv.w) - m4.w) * s4.w;
            if (aj == i) { p.x = 0.f; p.y = 0.f; p.z = 0.f; p.w = 0.f; }
            a_base_g[i * N_ + aj] = p;
        }
    }

    // ---- out epilogue ----
#pragma unroll
    for (int n = 0; n < 8; ++n) {
        int f = n * 16 + ls;
#pragma unroll
        for (int q = 0; q < 4; ++q)
            out[(size_t)(w * 16 + kg * 4 + q) * 65536 + (size_t)sp * NH_ + f] =
                aco[n][q] * 0.25f;
    }
}

// ---------------------------------------------------------------------------
extern "C" void kernel_launch(void* const* d_in, const int* in_sizes, int n_in,
                              void* d_out, int out_size, void* d_ws, size_t ws_size,
                              hipStream_t stream) {
    const float* hm = (const float*)d_in[0];
    const float* Wl = (const float*)d_in[1];
    const float* Wr = (const float*)d_in[2];
    const float* aw = (const float*)d_in[3];

    float* out   = (float*)d_out;
    float* a_out = out + OUT_ELEMS;

    char* ws = (char*)d_ws;
    float* sl  = (float*)ws;                                  // 1 MiB
    float* sr  = sl + SP_ * N_ * H_;                          // 1 MiB
    float* wls = sr + SP_ * N_ * H_;                          // 4 KiB
    float* wrs = wls + F_ * H_;                               // 4 KiB
    unsigned short* bth = (unsigned short*)(wrs + F_ * H_);   // 256 KiB
    unsigned short* btl = bth + GC_ * F_;                     // 256 KiB

    prep_kernel <<<8,           256, 0, stream>>>(Wl, Wr, aw, wls, wrs);
    prep_bt     <<<64,          256, 0, stream>>>(Wr, bth, btl);
    score_kernel<<<ROWS_ / 256, 256, 0, stream>>>(hm, wls, wrs, sl, sr);
    gat_fused   <<<SP_,         512, 0, stream>>>(sl, sr, hm, bth, btl, a_out, out);
}